// Round 1
// baseline (195.194 us; speedup 1.0000x reference)
//
#include <hip/hip_runtime.h>

#define BB 8
#define SS 4096
#define DD 768
#define NN 64
#define D4 (DD / 4)   // 192 float4 columns

// grid: (BB*NN, 3), block: 64 threads (one wave).
// Block (seg, g) owns float4 columns [g*64, g*64+64) of segment seg=(b,n):
//   - ragged mean over tokens [start, start+len) with exact per-feature
//     nonzero counts, all-zero fallback to wv[0,0,:]
//   - rep-token gather for the same columns
//   - (g==0, lane==0) writes the two mask scalars
__global__ __launch_bounds__(64) void pool_kernel(
    const float* __restrict__ wv,
    const int* __restrict__ rep_ids,
    const float* __restrict__ rep_mask,
    const int* __restrict__ lens,
    const float* __restrict__ len_mask,
    float* __restrict__ out)
{
    const int seg  = blockIdx.x;          // 0..BB*NN-1
    const int g    = blockIdx.y;          // 0..2
    const int b    = seg >> 6;
    const int n    = seg & 63;
    const int lane = threadIdx.x;         // 0..63

    // --- segment offsets: one coalesced load + wave prefix via butterfly sum ---
    int myLen = lens[b * NN + lane];
    int pre   = (lane < n) ? myLen : 0;
    #pragma unroll
    for (int off = 32; off; off >>= 1) pre += __shfl_xor(pre, off);
    const int start = pre;                 // sum of lens[b, 0..n-1]
    const int len   = __shfl(myLen, n);

    const int col4 = g * 64 + lane;        // 0..191
    const float4* wv4 = (const float4*)wv;
    const float4* p   = wv4 + (size_t)(b * SS + start) * D4 + col4;

    // --- ragged sum + per-feature nonzero count ---
    float4 sum = make_float4(0.f, 0.f, 0.f, 0.f);
    float4 cnt = make_float4(0.f, 0.f, 0.f, 0.f);
    #pragma unroll 4
    for (int t = 0; t < len; ++t) {
        float4 v = p[(size_t)t * D4];
        sum.x += v.x; sum.y += v.y; sum.z += v.z; sum.w += v.w;
        cnt.x += (v.x != 0.f) ? 1.f : 0.f;
        cnt.y += (v.y != 0.f) ? 1.f : 0.f;
        cnt.z += (v.z != 0.f) ? 1.f : 0.f;
        cnt.w += (v.w != 0.f) ? 1.f : 0.f;
    }

    float4 mean;
    mean.x = sum.x / fmaxf(cnt.x, 1.f);
    mean.y = sum.y / fmaxf(cnt.y, 1.f);
    mean.z = sum.z / fmaxf(cnt.z, 1.f);
    mean.w = sum.w / fmaxf(cnt.w, 1.f);

    // all-zero fallback (wave == block, so ballot is a block reduction)
    float tot = cnt.x + cnt.y + cnt.z + cnt.w;
    unsigned long long nz = __ballot(tot != 0.f);
    if (nz == 0ULL) {
        mean = wv4[col4];                  // wv[0,0,:] slice
    }

    const float lm = len_mask[b * NN + n];
    mean.x *= lm; mean.y *= lm; mean.z *= lm; mean.w *= lm;

    float4* out4 = (float4*)out;
    out4[(size_t)(b * 2 * NN + NN + n) * D4 + col4] = mean;

    // --- rep-token gather branch ---
    const int   rid = rep_ids[b * NN + n];
    const float rm  = rep_mask[b * NN + n];
    float4 rv = wv4[(size_t)(b * SS + rid) * D4 + col4];
    rv.x *= rm; rv.y *= rm; rv.z *= rm; rv.w *= rm;
    out4[(size_t)(b * 2 * NN + n) * D4 + col4] = rv;

    // --- masks tail of the flat output ---
    if (g == 0 && lane == 0) {
        float* masks = out + (size_t)BB * 2 * NN * DD;
        masks[b * 2 * NN + n]      = rm;
        masks[b * 2 * NN + NN + n] = lm;
    }
}

extern "C" void kernel_launch(void* const* d_in, const int* in_sizes, int n_in,
                              void* d_out, int out_size, void* d_ws, size_t ws_size,
                              hipStream_t stream) {
    const float* wv       = (const float*)d_in[0];
    const int*   rep_ids  = (const int*)d_in[1];
    const float* rep_mask = (const float*)d_in[2];
    const int*   lens     = (const int*)d_in[3];
    const float* len_mask = (const float*)d_in[4];
    float*       out      = (float*)d_out;

    dim3 grid(BB * NN, 3);
    pool_kernel<<<grid, 64, 0, stream>>>(wv, rep_ids, rep_mask, lens, len_mask, out);
}

// Round 5
// 158.997 us; speedup vs baseline: 1.2277x; 1.2277x over previous
//
#include <hip/hip_runtime.h>

#define BB 8
#define SS 4096
#define DD 768
#define NN 64
#define D4 (DD / 4)   // 192 float4 columns
#define WAVES 8
#define BLOCK (WAVES * 64)

// grid: (BB*NN, 3), block: 512 threads (8 waves).
// Block (seg, g) owns float4 columns [g*64, g*64+64) of segment seg=(b,n).
// The 8 waves split the segment's tokens stride-8; partial sum/cnt combined
// through LDS; wave 0 finishes (mean, fallback, rep gather, masks).
__global__ __launch_bounds__(BLOCK) void pool_kernel(
    const float* __restrict__ wv,
    const int* __restrict__ rep_ids,
    const float* __restrict__ rep_mask,
    const int* __restrict__ lens,
    const float* __restrict__ len_mask,
    float* __restrict__ out)
{
    __shared__ float4 s_sum[WAVES][64];
    __shared__ float4 s_cnt[WAVES][64];

    const int seg  = blockIdx.x;          // 0..BB*NN-1
    const int g    = blockIdx.y;          // 0..2
    const int b    = seg >> 6;
    const int n    = seg & 63;
    const int tid  = threadIdx.x;
    const int lane = tid & 63;
    const int w    = tid >> 6;            // 0..7 token-group

    // --- segment offsets: coalesced load + butterfly prefix (per wave) ---
    int myLen = lens[b * NN + lane];
    int pre   = (lane < n) ? myLen : 0;
    #pragma unroll
    for (int off = 32; off; off >>= 1) pre += __shfl_xor(pre, off);
    const int start = pre;                 // sum of lens[b, 0..n-1]
    const int len   = __shfl(myLen, n);

    const int col4 = g * 64 + lane;        // 0..191
    const float4* wv4 = (const float4*)wv;
    const float4* p   = wv4 + ((size_t)(b * SS + start) + w) * D4 + col4;

    // --- ragged sum + per-feature nonzero count, tokens strided by wave ---
    float4 sum = make_float4(0.f, 0.f, 0.f, 0.f);
    float4 cnt = make_float4(0.f, 0.f, 0.f, 0.f);
    #pragma unroll 8
    for (int t = w; t < len; t += WAVES) {
        float4 v = *p;
        p += (size_t)WAVES * D4;
        sum.x += v.x; sum.y += v.y; sum.z += v.z; sum.w += v.w;
        cnt.x += (v.x != 0.f) ? 1.f : 0.f;
        cnt.y += (v.y != 0.f) ? 1.f : 0.f;
        cnt.z += (v.z != 0.f) ? 1.f : 0.f;
        cnt.w += (v.w != 0.f) ? 1.f : 0.f;
    }

    s_sum[w][lane] = sum;
    s_cnt[w][lane] = cnt;
    __syncthreads();

    if (w == 0) {
        float4 S = make_float4(0.f, 0.f, 0.f, 0.f);
        float4 C = make_float4(0.f, 0.f, 0.f, 0.f);
        #pragma unroll
        for (int j = 0; j < WAVES; ++j) {
            float4 a = s_sum[j][lane];
            float4 c = s_cnt[j][lane];
            S.x += a.x; S.y += a.y; S.z += a.z; S.w += a.w;
            C.x += c.x; C.y += c.y; C.z += c.z; C.w += c.w;
        }

        float4 mean;
        mean.x = S.x / fmaxf(C.x, 1.f);
        mean.y = S.y / fmaxf(C.y, 1.f);
        mean.z = S.z / fmaxf(C.z, 1.f);
        mean.w = S.w / fmaxf(C.w, 1.f);

        // all-zero fallback (ballot across wave 0 = this block's 256 cols)
        float tot = C.x + C.y + C.z + C.w;
        unsigned long long nz = __ballot(tot != 0.f);
        if (nz == 0ULL) {
            mean = wv4[col4];              // wv[0,0,:] slice
        }

        const float lm = len_mask[b * NN + n];
        mean.x *= lm; mean.y *= lm; mean.z *= lm; mean.w *= lm;

        float4* out4 = (float4*)out;
        out4[(size_t)(b * 2 * NN + NN + n) * D4 + col4] = mean;

        // --- rep-token gather branch ---
        const int   rid = rep_ids[b * NN + n];
        const float rm  = rep_mask[b * NN + n];
        float4 rv = wv4[(size_t)(b * SS + rid) * D4 + col4];
        rv.x *= rm; rv.y *= rm; rv.z *= rm; rv.w *= rm;
        out4[(size_t)(b * 2 * NN + n) * D4 + col4] = rv;

        // --- masks tail of the flat output ---
        if (g == 0 && lane == 0) {
            float* masks = out + (size_t)BB * 2 * NN * DD;
            masks[b * 2 * NN + n]      = rm;
            masks[b * 2 * NN + NN + n] = lm;
        }
    }
}

extern "C" void kernel_launch(void* const* d_in, const int* in_sizes, int n_in,
                              void* d_out, int out_size, void* d_ws, size_t ws_size,
                              hipStream_t stream) {
    const float* wv       = (const float*)d_in[0];
    const int*   rep_ids  = (const int*)d_in[1];
    const float* rep_mask = (const float*)d_in[2];
    const int*   lens     = (const int*)d_in[3];
    const float* len_mask = (const float*)d_in[4];
    float*       out      = (float*)d_out;

    dim3 grid(BB * NN, 3);
    pool_kernel<<<grid, BLOCK, 0, stream>>>(wv, rep_ids, rep_mask, lens, len_mask, out);
}